// Round 6
// baseline (1193.144 us; speedup 1.0000x reference)
//
#include <hip/hip_runtime.h>

#define N_PTS 32768
#define DIM   128
#define M_CB  8
#define K_CB  256
#define MK    2048
#define N_ITER 3

// ---------------- Kernel 1: transpose C_pair ----------------
// Cpt[ij][b][k] = Cp[ij][k][b]   (so the ICM gather over k is contiguous)
__global__ __launch_bounds__(1024) void kpair_transpose(const float* __restrict__ Cp,
                                                        float* __restrict__ Cpt) {
    __shared__ float t[32][33];
    int ij = blockIdx.z;
    int b0 = blockIdx.x * 32, k0 = blockIdx.y * 32;
    int tx = threadIdx.x, ty = threadIdx.y;
    const size_t base = (size_t)ij * K_CB * K_CB;
    t[ty][tx] = Cp[base + (size_t)(k0 + ty) * K_CB + (b0 + tx)];
    __syncthreads();
    Cpt[base + (size_t)(b0 + ty) * K_CB + (k0 + tx)] = t[tx][ty];
}

// ---------------- Kernel 2: fp32 GEMM + fused unary add ----------------
// S[p][c] = -2 * sum_d X[n0+p][d]*C[c][d] + Cu[n0+p][c]
// 128x128 tile per 256-thread block, 8x8 micro-tile per thread, K=128 in 16 stages.
__global__ __launch_bounds__(256) void kgemm(const float* __restrict__ X,
                                             const float* __restrict__ C,
                                             const float* __restrict__ Cu,
                                             float* __restrict__ S, int n0) {
    __shared__ float As[8][128];
    __shared__ float Bs[8][128];
    const int t  = threadIdx.x;
    const int tx = t & 15;        // c direction
    const int ty = t >> 4;        // p direction
    const int c0 = blockIdx.x * 128;
    const int p0 = blockIdx.y * 128;

    float acc[8][8];
#pragma unroll
    for (int i = 0; i < 8; ++i)
#pragma unroll
        for (int j = 0; j < 8; ++j) acc[i][j] = 0.f;

    const int lp = t & 127;       // row within tile
    const int lg = t >> 7;        // which float4 of the 8-wide d-slab
    const float* xsrc = X + (size_t)(n0 + p0 + lp) * DIM + lg * 4;
    const float* csrc = C + (size_t)(c0 + lp) * DIM + lg * 4;

    for (int s = 0; s < 16; ++s) {
        float4 xa = *(const float4*)(xsrc + s * 8);
        float4 cb = *(const float4*)(csrc + s * 8);
        __syncthreads();
        As[lg * 4 + 0][lp] = xa.x; As[lg * 4 + 1][lp] = xa.y;
        As[lg * 4 + 2][lp] = xa.z; As[lg * 4 + 3][lp] = xa.w;
        Bs[lg * 4 + 0][lp] = cb.x; Bs[lg * 4 + 1][lp] = cb.y;
        Bs[lg * 4 + 2][lp] = cb.z; Bs[lg * 4 + 3][lp] = cb.w;
        __syncthreads();
#pragma unroll
        for (int dd = 0; dd < 8; ++dd) {
            float4 a0 = *(const float4*)&As[dd][ty * 8];
            float4 a1 = *(const float4*)&As[dd][ty * 8 + 4];
            float4 b0 = *(const float4*)&Bs[dd][tx * 8];
            float4 b1 = *(const float4*)&Bs[dd][tx * 8 + 4];
            float a[8] = {a0.x, a0.y, a0.z, a0.w, a1.x, a1.y, a1.z, a1.w};
            float b[8] = {b0.x, b0.y, b0.z, b0.w, b1.x, b1.y, b1.z, b1.w};
#pragma unroll
            for (int pi = 0; pi < 8; ++pi)
#pragma unroll
                for (int ci = 0; ci < 8; ++ci) acc[pi][ci] += a[pi] * b[ci];
        }
    }

#pragma unroll
    for (int pi = 0; pi < 8; ++pi) {
        size_t row = (size_t)(p0 + ty * 8 + pi);
        const float* cus = Cu + ((size_t)n0 + row) * MK + c0 + tx * 8;
        float4 u0 = *(const float4*)cus;
        float4 u1 = *(const float4*)(cus + 4);
        float* dst = S + row * MK + c0 + tx * 8;
        float4 o0 = make_float4(-2.f * acc[pi][0] + u0.x, -2.f * acc[pi][1] + u0.y,
                                -2.f * acc[pi][2] + u0.z, -2.f * acc[pi][3] + u0.w);
        float4 o1 = make_float4(-2.f * acc[pi][4] + u1.x, -2.f * acc[pi][5] + u1.y,
                                -2.f * acc[pi][6] + u1.z, -2.f * acc[pi][7] + u1.w);
        *(float4*)dst = o0;
        *(float4*)(dst + 4) = o1;
    }
}

// ---------------- Kernel 3: ICM, one wave per point ----------------
// Score base (x_ci + C_unary, 2048 floats) lives in 32 VGPRs/lane.
__global__ __launch_bounds__(256) void kicm(const float* __restrict__ S,
                                            const float* __restrict__ Cpt,
                                            const int* __restrict__ Bin,
                                            int* __restrict__ out, int n0) {
    const int l = threadIdx.x & 63;
    const int w = (int)((blockIdx.x * 256 + threadIdx.x) >> 6); // chunk-relative point
    const size_t n = (size_t)n0 + w;

    float4 s[8];
#pragma unroll
    for (int i = 0; i < 8; ++i)
        s[i] = *(const float4*)(S + (size_t)w * MK + i * K_CB + l * 4);

    int b[8];
#pragma unroll
    for (int j = 0; j < 8; ++j) b[j] = Bin[n * M_CB + j];

    for (int it = 0; it < N_ITER; ++it) {
#pragma unroll
        for (int i = 0; i < 8; ++i) {
            float4 r[8];
#pragma unroll
            for (int j = 0; j < 8; ++j) {
                size_t off = ((size_t)((i * M_CB + j) * K_CB + b[j])) * K_CB + l * 4;
                r[j] = *(const float4*)(Cpt + off);
            }
            float4 acc = s[i];
#pragma unroll
            for (int j = 0; j < 8; ++j) {
                acc.x += r[j].x; acc.y += r[j].y; acc.z += r[j].z; acc.w += r[j].w;
            }
            // lane-local argmin over 4 (ascending scan, strict < keeps first index)
            float v = acc.x; int idx = l * 4;
            if (acc.y < v) { v = acc.y; idx = l * 4 + 1; }
            if (acc.z < v) { v = acc.z; idx = l * 4 + 2; }
            if (acc.w < v) { v = acc.w; idx = l * 4 + 3; }
            // wave argmin, first-index tie-break (matches jnp.argmin)
#pragma unroll
            for (int off = 32; off > 0; off >>= 1) {
                float ov = __shfl_down(v, off);
                int   oi = __shfl_down(idx, off);
                if (ov < v || (ov == v && oi < idx)) { v = ov; idx = oi; }
            }
            idx = __shfl(idx, 0);
            b[i] = idx;
        }
    }

    if (l == 0) {
        int4 o0 = make_int4(b[0], b[1], b[2], b[3]);
        int4 o1 = make_int4(b[4], b[5], b[6], b[7]);
        *(int4*)(out + n * M_CB)     = o0;
        *(int4*)(out + n * M_CB + 4) = o1;
    }
}

extern "C" void kernel_launch(void* const* d_in, const int* in_sizes, int n_in,
                              void* d_out, int out_size, void* d_ws, size_t ws_size,
                              hipStream_t stream) {
    const float* X  = (const float*)d_in[0];
    const float* C  = (const float*)d_in[1];
    const float* Cu = (const float*)d_in[2];
    const float* Cp = (const float*)d_in[3];
    const int*   B  = (const int*)d_in[4];
    int* out = (int*)d_out;

    float* wsf = (float*)d_ws;
    const size_t CPT_ELEMS = (size_t)M_CB * M_CB * K_CB * K_CB; // 4 Mi floats = 16 MB
    float* Cpt = wsf;
    float* S   = wsf + CPT_ELEMS;

    // Chunk the n dimension so the score scratch fits in ws.
    size_t spare_bytes = ws_size > CPT_ELEMS * 4 ? ws_size - CPT_ELEMS * 4 : 0;
    long long chunk = (long long)(spare_bytes / ((size_t)MK * 4));
    if (chunk > N_PTS) chunk = N_PTS;
    chunk = (chunk / 128) * 128;
    if (chunk < 128) chunk = 128; // minimal viable chunk

    kpair_transpose<<<dim3(8, 8, 64), dim3(32, 32), 0, stream>>>(Cp, Cpt);

    for (int n0 = 0; n0 < N_PTS; n0 += (int)chunk) {
        int P = (int)((N_PTS - n0 < chunk) ? (N_PTS - n0) : chunk);
        kgemm<<<dim3(MK / 128, P / 128), 256, 0, stream>>>(X, C, Cu, S, n0);
        kicm<<<P / 4, 256, 0, stream>>>(S, Cpt, B, out, n0);
    }
}

// Round 7
// 995.019 us; speedup vs baseline: 1.1991x; 1.1991x over previous
//
#include <hip/hip_runtime.h>

#define N_PTS 32768
#define DIM   128
#define M_CB  8
#define K_CB  256
#define MK    2048
#define N_ITER 3

// ---------------- Kernel 1: transpose C_pair ----------------
// Cpt[ij][b][k] = Cp[ij][k][b]   (so the ICM gather over k is contiguous)
__global__ __launch_bounds__(1024) void kpair_transpose(const float* __restrict__ Cp,
                                                        float* __restrict__ Cpt) {
    __shared__ float t[32][33];
    int ij = blockIdx.z;
    int b0 = blockIdx.x * 32, k0 = blockIdx.y * 32;
    int tx = threadIdx.x, ty = threadIdx.y;
    const size_t base = (size_t)ij * K_CB * K_CB;
    t[ty][tx] = Cp[base + (size_t)(k0 + ty) * K_CB + (b0 + tx)];
    __syncthreads();
    Cpt[base + (size_t)(b0 + ty) * K_CB + (k0 + tx)] = t[tx][ty];
}

// ---------------- Kernel 2: fp32 GEMM + fused unary add (unchanged, passing) ----
// S[p][c] = -2 * sum_d X[n0+p][d]*C[c][d] + Cu[n0+p][c]
__global__ __launch_bounds__(256) void kgemm(const float* __restrict__ X,
                                             const float* __restrict__ C,
                                             const float* __restrict__ Cu,
                                             float* __restrict__ S, int n0) {
    __shared__ float As[8][128];
    __shared__ float Bs[8][128];
    const int t  = threadIdx.x;
    const int tx = t & 15;        // c direction
    const int ty = t >> 4;        // p direction
    const int c0 = blockIdx.x * 128;
    const int p0 = blockIdx.y * 128;

    float acc[8][8];
#pragma unroll
    for (int i = 0; i < 8; ++i)
#pragma unroll
        for (int j = 0; j < 8; ++j) acc[i][j] = 0.f;

    const int lp = t & 127;       // row within tile
    const int lg = t >> 7;        // which float4 of the 8-wide d-slab
    const float* xsrc = X + (size_t)(n0 + p0 + lp) * DIM + lg * 4;
    const float* csrc = C + (size_t)(c0 + lp) * DIM + lg * 4;

    for (int s = 0; s < 16; ++s) {
        float4 xa = *(const float4*)(xsrc + s * 8);
        float4 cb = *(const float4*)(csrc + s * 8);
        __syncthreads();
        As[lg * 4 + 0][lp] = xa.x; As[lg * 4 + 1][lp] = xa.y;
        As[lg * 4 + 2][lp] = xa.z; As[lg * 4 + 3][lp] = xa.w;
        Bs[lg * 4 + 0][lp] = cb.x; Bs[lg * 4 + 1][lp] = cb.y;
        Bs[lg * 4 + 2][lp] = cb.z; Bs[lg * 4 + 3][lp] = cb.w;
        __syncthreads();
#pragma unroll
        for (int dd = 0; dd < 8; ++dd) {
            float4 a0 = *(const float4*)&As[dd][ty * 8];
            float4 a1 = *(const float4*)&As[dd][ty * 8 + 4];
            float4 b0 = *(const float4*)&Bs[dd][tx * 8];
            float4 b1 = *(const float4*)&Bs[dd][tx * 8 + 4];
            float a[8] = {a0.x, a0.y, a0.z, a0.w, a1.x, a1.y, a1.z, a1.w};
            float b[8] = {b0.x, b0.y, b0.z, b0.w, b1.x, b1.y, b1.z, b1.w};
#pragma unroll
            for (int pi = 0; pi < 8; ++pi)
#pragma unroll
                for (int ci = 0; ci < 8; ++ci) acc[pi][ci] += a[pi] * b[ci];
        }
    }

#pragma unroll
    for (int pi = 0; pi < 8; ++pi) {
        size_t row = (size_t)(p0 + ty * 8 + pi);
        const float* cus = Cu + ((size_t)n0 + row) * MK + c0 + tx * 8;
        float4 u0 = *(const float4*)cus;
        float4 u1 = *(const float4*)(cus + 4);
        float* dst = S + row * MK + c0 + tx * 8;
        float4 o0 = make_float4(-2.f * acc[pi][0] + u0.x, -2.f * acc[pi][1] + u0.y,
                                -2.f * acc[pi][2] + u0.z, -2.f * acc[pi][3] + u0.w);
        float4 o1 = make_float4(-2.f * acc[pi][4] + u1.x, -2.f * acc[pi][5] + u1.y,
                                -2.f * acc[pi][6] + u1.z, -2.f * acc[pi][7] + u1.w);
        *(float4*)dst = o0;
        *(float4*)(dst + 4) = o1;
    }
}

// ---------------- Kernel 3: ONE phased ICM update (codebook i) ----------------
// All concurrent waves gather from the same 2 MB Cpt slice -> per-XCD-L2 resident.
// B state lives in `out` (seeded from input B); identical summation order to the
// monolithic version -> bit-identical scores and argmin.
__global__ __launch_bounds__(256) void kupdate(const float* __restrict__ S,
                                               const float* __restrict__ Cpt,
                                               int* __restrict__ B,
                                               int n0, int i) {
    const int l = threadIdx.x & 63;
    const int w = (int)((blockIdx.x * 256 + threadIdx.x) >> 6); // chunk-relative point
    const size_t n = (size_t)n0 + w;

    const int4 b0 = *(const int4*)(B + n * M_CB);
    const int4 b1 = *(const int4*)(B + n * M_CB + 4);
    const int b[8] = {b0.x, b0.y, b0.z, b0.w, b1.x, b1.y, b1.z, b1.w};

    float4 acc = *(const float4*)(S + (size_t)w * MK + i * K_CB + l * 4);
    const float* cslice = Cpt + (size_t)i * M_CB * K_CB * K_CB;

    float4 r[8];
#pragma unroll
    for (int j = 0; j < 8; ++j)
        r[j] = *(const float4*)(cslice + ((size_t)(j * K_CB + b[j])) * K_CB + l * 4);
#pragma unroll
    for (int j = 0; j < 8; ++j) {
        acc.x += r[j].x; acc.y += r[j].y; acc.z += r[j].z; acc.w += r[j].w;
    }

    // lane-local argmin over 4 (ascending scan, strict < keeps first index)
    float v = acc.x; int idx = l * 4;
    if (acc.y < v) { v = acc.y; idx = l * 4 + 1; }
    if (acc.z < v) { v = acc.z; idx = l * 4 + 2; }
    if (acc.w < v) { v = acc.w; idx = l * 4 + 3; }
    // wave argmin, first-index tie-break (matches jnp.argmin)
#pragma unroll
    for (int off = 32; off > 0; off >>= 1) {
        float ov = __shfl_down(v, off);
        int   oi = __shfl_down(idx, off);
        if (ov < v || (ov == v && oi < idx)) { v = ov; idx = oi; }
    }
    if (l == 0) B[n * M_CB + i] = idx;
}

extern "C" void kernel_launch(void* const* d_in, const int* in_sizes, int n_in,
                              void* d_out, int out_size, void* d_ws, size_t ws_size,
                              hipStream_t stream) {
    const float* X  = (const float*)d_in[0];
    const float* C  = (const float*)d_in[1];
    const float* Cu = (const float*)d_in[2];
    const float* Cp = (const float*)d_in[3];
    const int*   B  = (const int*)d_in[4];
    int* out = (int*)d_out;

    float* wsf = (float*)d_ws;
    const size_t CPT_ELEMS = (size_t)M_CB * M_CB * K_CB * K_CB; // 4 Mi floats = 16 MB
    float* Cpt = wsf;
    float* S   = wsf + CPT_ELEMS;

    // Chunk the n dimension so the score scratch fits in ws.
    size_t spare_bytes = ws_size > CPT_ELEMS * 4 ? ws_size - CPT_ELEMS * 4 : 0;
    long long chunk = (long long)(spare_bytes / ((size_t)MK * 4));
    if (chunk > N_PTS) chunk = N_PTS;
    chunk = (chunk / 128) * 128;
    if (chunk < 128) chunk = 128; // minimal viable chunk

    kpair_transpose<<<dim3(8, 8, 64), dim3(32, 32), 0, stream>>>(Cp, Cpt);

    // Seed the working B state in d_out (re-poisoned before every call).
    hipMemcpyAsync(out, B, (size_t)N_PTS * M_CB * sizeof(int),
                   hipMemcpyDeviceToDevice, stream);

    for (int n0 = 0; n0 < N_PTS; n0 += (int)chunk) {
        int P = (int)((N_PTS - n0 < chunk) ? (N_PTS - n0) : chunk);
        kgemm<<<dim3(MK / 128, P / 128), 256, 0, stream>>>(X, C, Cu, S, n0);
        for (int it = 0; it < N_ITER; ++it)
            for (int i = 0; i < M_CB; ++i)
                kupdate<<<P / 4, 256, 0, stream>>>(S, Cpt, out, n0, i);
    }
}